// Round 4
// baseline (1445.493 us; speedup 1.0000x reference)
//
#include <hip/hip_runtime.h>
#include <math.h>

#define C 64
#define K 20
#define BSTR 72        // Bs row stride (shorts): 144 B, 16B-aligned b128 frag reads

// fallback path constants
#define P1_TPB 128
#define P1_ROWS 128
#define LSTR 65

typedef __attribute__((ext_vector_type(8))) short bf16x8;
typedef __attribute__((ext_vector_type(4))) float f32x4;

// ---------------- helpers ----------------

__device__ __forceinline__ float wave_reduce_add(float v) {
#pragma unroll
  for (int m = 32; m > 0; m >>= 1) v += __shfl_xor(v, m, 64);
  return v;
}

__device__ __forceinline__ unsigned short f2bf16(float x) {
  union { float f; unsigned u; } v; v.f = x;
  unsigned r = v.u + 0x7FFFu + ((v.u >> 16) & 1u);   // RTNE
  return (unsigned short)(r >> 16);
}

// truncation-pack two floats -> (bf16(lo) | bf16(hi)<<16), single v_perm_b32
__device__ __forceinline__ unsigned pack_bf16_trunc(float lo, float hi) {
  return __builtin_amdgcn_perm(__float_as_uint(hi), __float_as_uint(lo), 0x07060302u);
}

__device__ __forceinline__ float bf16lo(unsigned u) { return __uint_as_float(u << 16); }
__device__ __forceinline__ float bf16hi(unsigned u) { return __uint_as_float(u & 0xFFFF0000u); }

// acc layout (floats): [0]=sum w*nll [1]=sum w [2]=sum l1*m [3]=sum cos*m [4]=sum m
// [8..71]=sum_h  [72..135]=sum_h2  [136..199]=BN scale  [200..263]=BN shift

// ---------------- pass 1: direct-frag MFMA dual-GEMM + stats + CE + C-layout spill ----
// b1 dropped: BN(train) output invariant to constant channel shift.
// Spill layout (ushorts): tile*16384 + (wv*4+rt)*1024 + ct*256 + L*4 + r
//   where point = wv*64+rt*16+(L>>4)*4+r, ch = ct*16+(L&15)  (MFMA C-layout)

__global__ __launch_bounds__(256, 4)
void pass1_kernel(const float* __restrict__ feat,
                  const int* __restrict__ segment,
                  const float* __restrict__ W1,
                  const float* __restrict__ Wseg,
                  const float* __restrict__ bseg,
                  const float* __restrict__ cw,
                  float* __restrict__ acc,
                  unsigned short* __restrict__ hout,
                  int store_h) {
  __shared__ __align__(16) unsigned short Bs[96 * BSTR];  // W1^T rows 0..63, Wseg^T 64..95
  __shared__ unsigned short lgL[256 * 22];                // wave-private logit rows
  __shared__ float cs1[4][64], cs2[4][64];

  const int t = threadIdx.x;
  const int wv = t >> 6, L = t & 63, colL = L & 15, quad = L >> 4;
  const long long tile = blockIdx.x;
  const long long base = tile << 8;

  // 1) issue all A loads first (coalesced: 16 rows x 128B per instr pair)
  const float* ap = feat + ((base + wv * 64 + colL) << 6) + quad * 8;
  float4 ar[4][2][2];
#pragma unroll
  for (int rt = 0; rt < 4; ++rt)
#pragma unroll
    for (int kh = 0; kh < 2; ++kh) {
      const float* q = ap + rt * 1024 + kh * 32;
      ar[rt][kh][0] = *(const float4*)q;
      ar[rt][kh][1] = *(const float4*)(q + 4);
    }

  // 2) stage B (RTNE, once per block) while A loads fly
#pragma unroll
  for (int i = 0; i < 16; ++i) {
    int e = t + i * 256;                         // e = k*64 + j
    Bs[(e & 63) * BSTR + (e >> 6)] = f2bf16(W1[e]);
  }
#pragma unroll
  for (int i = 0; i < 8; ++i) {
    int e = t + i * 256;                         // 64 x 32 padded
    int k = e >> 5, j = e & 31;
    Bs[(64 + j) * BSTR + k] = f2bf16(j < K ? Wseg[k * K + j] : 0.0f);
  }
  __syncthreads();

  // 3) convert A to bf16 fragments (v_perm truncation)
  bf16x8 af[4][2];
#pragma unroll
  for (int rt = 0; rt < 4; ++rt)
#pragma unroll
    for (int kh = 0; kh < 2; ++kh) {
      union { uint4 u; bf16x8 v; } cv;
      float4 a0 = ar[rt][kh][0], a1 = ar[rt][kh][1];
      cv.u.x = pack_bf16_trunc(a0.x, a0.y);
      cv.u.y = pack_bf16_trunc(a0.z, a0.w);
      cv.u.z = pack_bf16_trunc(a1.x, a1.y);
      cv.u.w = pack_bf16_trunc(a1.z, a1.w);
      af[rt][kh] = cv.v;
    }

  // 4) per-ct MFMA + immediate epilogue (only 16 acc VGPRs live)
  float s1[4] = {0, 0, 0, 0}, s2[4] = {0, 0, 0, 0};
  unsigned short* hb = hout + (tile << 14) + wv * 4096 + L * 4;
#pragma unroll
  for (int ct = 0; ct < 6; ++ct) {
    bf16x8 b0 = *(const bf16x8*)(Bs + (ct * 16 + colL) * BSTR + quad * 8);
    bf16x8 b1 = *(const bf16x8*)(Bs + (ct * 16 + colL) * BSTR + 32 + quad * 8);
    f32x4 a4[4];
#pragma unroll
    for (int rt = 0; rt < 4; ++rt) {
      f32x4 z = {0.f, 0.f, 0.f, 0.f};
      z = __builtin_amdgcn_mfma_f32_16x16x32_bf16(af[rt][0], b0, z, 0, 0, 0);
      z = __builtin_amdgcn_mfma_f32_16x16x32_bf16(af[rt][1], b1, z, 0, 0, 0);
      a4[rt] = z;
    }
    if (ct < 4) {
#pragma unroll
      for (int rt = 0; rt < 4; ++rt) {
        f32x4 v = a4[rt];
        s1[ct] += (v[0] + v[1]) + (v[2] + v[3]);
        float q2 = v[0] * v[0];
        q2 = __builtin_fmaf(v[1], v[1], q2);
        q2 = __builtin_fmaf(v[2], v[2], q2);
        q2 = __builtin_fmaf(v[3], v[3], q2);
        s2[ct] += q2;
        if (store_h) {
          uint2 o;
          o.x = pack_bf16_trunc(v[0], v[1]);
          o.y = pack_bf16_trunc(v[2], v[3]);
          *(uint2*)(hb + rt * 1024 + ct * 256) = o;
        }
      }
    } else {
#pragma unroll
      for (int rt = 0; rt < 4; ++rt) {
        f32x4 v = a4[rt];
        int row0 = wv * 64 + rt * 16 + quad * 4;
        if (ct == 4) {
#pragma unroll
          for (int r = 0; r < 4; ++r)
            lgL[(row0 + r) * 22 + colL] = (unsigned short)(__float_as_uint(v[r]) >> 16);
        } else if (colL < K - 16) {
#pragma unroll
          for (int r = 0; r < 4; ++r)
            lgL[(row0 + r) * 22 + 16 + colL] = (unsigned short)(__float_as_uint(v[r]) >> 16);
        }
      }
    }
  }

  // 5) stats: reduce over quads, park per-wave sums in LDS
#pragma unroll
  for (int ct = 0; ct < 4; ++ct) {
    float a1 = s1[ct]; a1 += __shfl_xor(a1, 16, 64); a1 += __shfl_xor(a1, 32, 64);
    float a2 = s2[ct]; a2 += __shfl_xor(a2, 16, 64); a2 += __shfl_xor(a2, 32, 64);
    if (L < 16) { cs1[wv][ct * 16 + L] = a1; cs2[wv][ct * 16 + L] = a2; }
  }
  __syncthreads();

  // 6) CE from wave-private logit rows
  {
    float lg[K];
    const unsigned* lrow = (const unsigned*)lgL + t * 11;
#pragma unroll
    for (int u = 0; u < K / 2; ++u) {
      unsigned q = lrow[u];
      lg[2 * u]     = bf16lo(q) + bseg[2 * u];
      lg[2 * u + 1] = bf16hi(q) + bseg[2 * u + 1];
    }
    const int seg = segment[base + t];
    const bool valid = (seg != -1);
    const int tgt = valid ? seg : 0;
    float mx = lg[0], lt = lg[0];
#pragma unroll
    for (int c = 1; c < K; ++c) { mx = fmaxf(mx, lg[c]); lt = (c == tgt) ? lg[c] : lt; }
    float se = 0.f;
#pragma unroll
    for (int c = 0; c < K; ++c) se += __expf(lg[c] - mx);
    float nll = mx + __logf(se) - lt;
    float w = valid ? cw[tgt] : 0.f;
    float rwn = wave_reduce_add(w * nll);
    float rw = wave_reduce_add(w);
    if (L == 0) { atomicAdd(&acc[0], rwn); atomicAdd(&acc[1], rw); }
  }

  // 7) per-block stats atomics
  if (t < 64) {
    atomicAdd(&acc[8 + t], cs1[0][t] + cs1[1][t] + cs1[2][t] + cs1[3][t]);
  } else if (t < 128) {
    int j = t - 64;
    atomicAdd(&acc[72 + j], cs2[0][j] + cs2[1][j] + cs2[2][j] + cs2[3][j]);
  }
}

// ---------------- prep: fold BN stats into scale/shift ----------------

__global__ void prep_kernel(const float* __restrict__ gamma,
                            const float* __restrict__ beta,
                            float* __restrict__ acc, int n) {
  int j = threadIdx.x;
  float inv_n = 1.0f / (float)n;
  float mean = acc[8 + j] * inv_n;
  float var = fmaxf(acc[72 + j] * inv_n - mean * mean, 0.0f);
  float sc = gamma[j] * rsqrtf(var + 1e-3f);
  acc[136 + j] = sc;
  acc[200 + j] = beta[j] - mean * sc;
}

// ---------------- pass 2: C-layout readback, no LDS, no barriers ----------------

__global__ __launch_bounds__(256, 4)
void pass2_from_h(const unsigned short* __restrict__ hsrc,
                  const float* __restrict__ coord,
                  const int* __restrict__ instance,
                  const float* __restrict__ centroid,
                  const float* __restrict__ W2,
                  const float* __restrict__ b2,
                  float* __restrict__ acc) {
  const int t = threadIdx.x;
  const int wv = t >> 6, L = t & 63, colL = L & 15, quad = L >> 4;
  const long long tile = blockIdx.x;

  // loss inputs: 1 point per lane (issued first)
  const int myrt = colL >> 2, myr = colL & 3;
  const long long p = (tile << 8) + wv * 64 + myrt * 16 + quad * 4 + myr;
  float cx = coord[p * 3], cy = coord[p * 3 + 1], cz = coord[p * 3 + 2];
  float ex = centroid[p * 3], ey = centroid[p * 3 + 1], ez = centroid[p * 3 + 2];
  int inst = instance[p];

  // all h loads (coalesced 512B per instr)
  const unsigned short* hb = hsrc + (tile << 14) + wv * 4096 + L * 4;
  uint2 hd[4][4];
#pragma unroll
  for (int rt = 0; rt < 4; ++rt)
#pragma unroll
    for (int ct = 0; ct < 4; ++ct)
      hd[rt][ct] = *(const uint2*)(hb + rt * 1024 + ct * 256);

  // per-lane BN + W2 coefficients (ch = ct*16+colL)
  float sc[4], sh[4], w2c[4][3];
#pragma unroll
  for (int ct = 0; ct < 4; ++ct) {
    int ch = ct * 16 + colL;
    sc[ct] = acc[136 + ch];
    sh[ct] = acc[200 + ch];
    w2c[ct][0] = W2[ch * 3];
    w2c[ct][1] = W2[ch * 3 + 1];
    w2c[ct][2] = W2[ch * 3 + 2];
  }

  float mybp[3] = {0.f, 0.f, 0.f};
#pragma unroll
  for (int rt = 0; rt < 4; ++rt) {
    float bp[4][3] = {{0,0,0},{0,0,0},{0,0,0},{0,0,0}};
#pragma unroll
    for (int ct = 0; ct < 4; ++ct) {
      uint2 q = hd[rt][ct];
      float v[4] = { bf16lo(q.x), bf16hi(q.x), bf16lo(q.y), bf16hi(q.y) };
#pragma unroll
      for (int r = 0; r < 4; ++r) {
        float y = fmaxf(__builtin_fmaf(v[r], sc[ct], sh[ct]), 0.0f);
        bp[r][0] = __builtin_fmaf(y, w2c[ct][0], bp[r][0]);
        bp[r][1] = __builtin_fmaf(y, w2c[ct][1], bp[r][1]);
        bp[r][2] = __builtin_fmaf(y, w2c[ct][2], bp[r][2]);
      }
    }
    // reduce over the 16 channel-lanes (colL bits)
#pragma unroll
    for (int m = 1; m < 16; m <<= 1)
#pragma unroll
      for (int r = 0; r < 4; ++r) {
        bp[r][0] += __shfl_xor(bp[r][0], m, 64);
        bp[r][1] += __shfl_xor(bp[r][1], m, 64);
        bp[r][2] += __shfl_xor(bp[r][2], m, 64);
      }
    if (rt == myrt) {
#pragma unroll
      for (int r = 0; r < 4; ++r)
        if (r == myr) { mybp[0] = bp[r][0]; mybp[1] = bp[r][1]; mybp[2] = bp[r][2]; }
    }
  }
  float bp0 = mybp[0] + b2[0], bp1 = mybp[1] + b2[1], bp2 = mybp[2] + b2[2];

  float gx = ex - cx, gy = ey - cy, gz = ez - cz;
  float m = (inst != -1) ? 1.0f : 0.0f;
  float l1 = fabsf(bp0 - gx) + fabsf(bp1 - gy) + fabsf(bp2 - gz);
  float npn = sqrtf(bp0 * bp0 + bp1 * bp1 + bp2 * bp2) + 1e-8f;
  float ngn = sqrtf(gx * gx + gy * gy + gz * gz) + 1e-8f;
  float cs = -(bp0 * gx + bp1 * gy + bp2 * gz) / (npn * ngn);

  float r0 = wave_reduce_add(l1 * m);
  float r1 = wave_reduce_add(cs * m);
  float r2 = wave_reduce_add(m);
  if (L == 0) {
    atomicAdd(&acc[2], r0);
    atomicAdd(&acc[3], r1);
    atomicAdd(&acc[4], r2);
  }
}

// ---------------- pass 2 fallback: recompute h from feat ----------------

__global__ __launch_bounds__(P1_TPB, 2)
void pass2_recompute(const float* __restrict__ feat,
                     const float* __restrict__ coord,
                     const int* __restrict__ instance,
                     const float* __restrict__ centroid,
                     const float* __restrict__ W1,
                     const float* __restrict__ W2,
                     const float* __restrict__ b2,
                     float* __restrict__ acc) {
  __shared__ float lds[P1_ROWS * LSTR];
  __shared__ float part[2][3];
  const int tid = threadIdx.x;
  const int wave = tid >> 6, lane = tid & 63;
  const long long base = (long long)blockIdx.x * P1_ROWS;

  {
    const float4* src = (const float4*)(feat + base * C);
#pragma unroll
    for (int i = 0; i < 16; ++i) {
      int g = tid + i * P1_TPB;
      float4 v = src[g];
      float* d = &lds[(g >> 4) * LSTR + ((g & 15) << 2)];
      d[0] = v.x; d[1] = v.y; d[2] = v.z; d[3] = v.w;
    }
  }
  __syncthreads();

  float h[C];
#pragma unroll
  for (int j = 0; j < C; ++j) h[j] = 0.0f;
  const float* frow = &lds[tid * LSTR];
#pragma unroll 4
  for (int k = 0; k < C; ++k) {
    float fk = frow[k];
#pragma unroll
    for (int j = 0; j < C; ++j) h[j] = __builtin_fmaf(fk, W1[k * C + j], h[j]);
  }

  const float* ssc = acc + 136;
  const float* ssh = acc + 200;
  float bp0 = b2[0], bp1 = b2[1], bp2 = b2[2];
#pragma unroll
  for (int j = 0; j < C; ++j) {
    float y = fmaxf(__builtin_fmaf(h[j], ssc[j], ssh[j]), 0.0f);
    bp0 = __builtin_fmaf(y, W2[j * 3 + 0], bp0);
    bp1 = __builtin_fmaf(y, W2[j * 3 + 1], bp1);
    bp2 = __builtin_fmaf(y, W2[j * 3 + 2], bp2);
  }

  const long long p = base + tid;
  float cx = coord[p * 3], cy = coord[p * 3 + 1], cz = coord[p * 3 + 2];
  float gx = centroid[p * 3] - cx, gy = centroid[p * 3 + 1] - cy, gz = centroid[p * 3 + 2] - cz;
  float m = (instance[p] != -1) ? 1.0f : 0.0f;
  float l1 = fabsf(bp0 - gx) + fabsf(bp1 - gy) + fabsf(bp2 - gz);
  float npn = sqrtf(bp0 * bp0 + bp1 * bp1 + bp2 * bp2) + 1e-8f;
  float ngn = sqrtf(gx * gx + gy * gy + gz * gz) + 1e-8f;
  float cs = -(bp0 * gx + bp1 * gy + bp2 * gz) / (npn * ngn);

  float r0 = wave_reduce_add(l1 * m);
  float r1 = wave_reduce_add(cs * m);
  float r2 = wave_reduce_add(m);
  if (lane == 0) { part[wave][0] = r0; part[wave][1] = r1; part[wave][2] = r2; }
  __syncthreads();
  if (tid == 0) {
    atomicAdd(&acc[2], part[0][0] + part[1][0]);
    atomicAdd(&acc[3], part[0][1] + part[1][1]);
    atomicAdd(&acc[4], part[0][2] + part[1][2]);
  }
}

// ---------------- finalize ----------------

__global__ void finalize_kernel(const float* __restrict__ acc, float* __restrict__ out) {
  if (threadIdx.x == 0 && blockIdx.x == 0) {
    float seg = acc[0] / acc[1];
    float den = acc[4] + 1e-8f;
    float l1 = acc[2] / den;
    float cs = acc[3] / den;
    out[0] = seg + l1 + cs;
    out[1] = seg;
    out[2] = l1;
    out[3] = cs;
  }
}

// ---------------- launch ----------------

extern "C" void kernel_launch(void* const* d_in, const int* in_sizes, int n_in,
                              void* d_out, int out_size, void* d_ws, size_t ws_size,
                              hipStream_t stream) {
  const float* feat = (const float*)d_in[0];
  const float* coord = (const float*)d_in[1];
  const int* segment = (const int*)d_in[2];
  const int* instance = (const int*)d_in[3];
  const float* centroid = (const float*)d_in[4];
  const float* W1 = (const float*)d_in[5];
  // d_in[6] = b1 : unused (BN shift-invariance)
  const float* gamma = (const float*)d_in[7];
  const float* beta = (const float*)d_in[8];
  const float* W2 = (const float*)d_in[9];
  const float* b2 = (const float*)d_in[10];
  const float* Wseg = (const float*)d_in[11];
  const float* bseg = (const float*)d_in[12];
  const float* cw = (const float*)d_in[13];

  const int n = in_sizes[0] / C;  // 1048576
  const int tiles = n / 256;

  float* acc = (float*)d_ws;
  unsigned short* hbuf = (unsigned short*)((char*)d_ws + 2048);
  const size_t need = 2048 + (size_t)n * C * sizeof(unsigned short);
  const int store_h = (ws_size >= need) ? 1 : 0;

  size_t zbytes = ws_size < 2048 ? ws_size : 2048;
  hipMemsetAsync(d_ws, 0, zbytes, stream);

  pass1_kernel<<<tiles, 256, 0, stream>>>(feat, segment, W1, Wseg, bseg, cw,
                                          acc, hbuf, store_h);
  prep_kernel<<<1, 64, 0, stream>>>(gamma, beta, acc, n);
  if (store_h) {
    pass2_from_h<<<tiles, 256, 0, stream>>>(hbuf, coord, instance, centroid, W2, b2, acc);
  } else {
    pass2_recompute<<<n / P1_ROWS, P1_TPB, 0, stream>>>(feat, coord, instance, centroid,
                                                        W1, W2, b2, acc);
  }
  finalize_kernel<<<1, 1, 0, stream>>>(acc, (float*)d_out);
}